// Round 1
// baseline (691.961 us; speedup 1.0000x reference)
//
#include <hip/hip_runtime.h>
#include <math.h>

// EnhancedTripletLoss: B=8192 anchors, D=256, 8 classes.
// loss = mean over valid anchors of relu( ||a-p+eps|| - ||a-n+eps|| + 0.3 )
// p = farthest same-label (not self), n = closest other-label, mined on the
// Gram-trick distance matrix (selection done on v = sq_j - 2*dot, monotone).

#define B_N 8192
#define D_K 256
#define NJ  8        // j-splits (grid.y): 512 blocks total = 2 blocks/CU
#define TI  128      // anchor rows per block
#define TJ  128      // j cols per subtile
#define KB  16       // k-chunk staged in LDS
#define LDA 132      // TI + 4 pad: float4-aligned rows, 2-way max bank alias

// ---------------- row squared norms ----------------
__global__ void k_rowsq(const float* __restrict__ x, float* __restrict__ sq) {
  int row  = blockIdx.x * 4 + (threadIdx.x >> 6);
  int lane = threadIdx.x & 63;
  float4 v = *reinterpret_cast<const float4*>(x + (size_t)row * D_K + lane * 4);
  float s = v.x * v.x + v.y * v.y + v.z * v.z + v.w * v.w;
#pragma unroll
  for (int off = 32; off > 0; off >>= 1) s += __shfl_down(s, off, 64);
  if (lane == 0) sq[row] = s;
}

// ---------------- fused distance + hard mining ----------------
// Each block: 128 anchors x (8192/NJ) candidates. 8x8 microtile per thread.
// Microtile columns are split {4tx..4tx+3, 64+4tx..}: keeps LDS reads 2-way.
__global__ __launch_bounds__(256, 2) void k_mine(
    const float* __restrict__ x, const int* __restrict__ lab,
    const float* __restrict__ sq,
    float* __restrict__ pv, int* __restrict__ pi,
    float* __restrict__ nv, int* __restrict__ ni) {
  __shared__ float As[KB][LDA];
  __shared__ float Bs[KB][LDA];

  const int tid = threadIdx.x;
  const int tx  = tid & 15;
  const int ty  = tid >> 4;
  const int i0   = blockIdx.x * TI;
  const int jblk = blockIdx.y * (B_N / NJ);

  int ioff[8], joff[8];
#pragma unroll
  for (int r = 0; r < 4; ++r) { ioff[r] = 4 * ty + r; ioff[r + 4] = 64 + 4 * ty + r; }
#pragma unroll
  for (int c = 0; c < 4; ++c) { joff[c] = 4 * tx + c; joff[c + 4] = 64 + 4 * tx + c; }

  int li[8];
#pragma unroll
  for (int r = 0; r < 8; ++r) li[r] = lab[i0 + ioff[r]];

  float bpv[8], bnv[8];
  int   bpi[8], bni[8];
#pragma unroll
  for (int r = 0; r < 8; ++r) { bpv[r] = -1e30f; bnv[r] = 1e30f; bpi[r] = -1; bni[r] = -1; }

  for (int sub = 0; sub < (B_N / NJ) / TJ; ++sub) {
    const int j0 = jblk + sub * TJ;
    float acc[64];
#pragma unroll
    for (int q = 0; q < 64; ++q) acc[q] = 0.f;

    for (int k0 = 0; k0 < D_K; k0 += KB) {
      // stage 128x16 of A and B, transposed into LDS
#pragma unroll
      for (int l = 0; l < 2; ++l) {
        int t   = tid + l * 256;
        int row = t >> 2;
        int c4  = (t & 3) * 4;
        float4 av = *reinterpret_cast<const float4*>(x + (size_t)(i0 + row) * D_K + k0 + c4);
        float4 bv = *reinterpret_cast<const float4*>(x + (size_t)(j0 + row) * D_K + k0 + c4);
        As[c4 + 0][row] = av.x; As[c4 + 1][row] = av.y;
        As[c4 + 2][row] = av.z; As[c4 + 3][row] = av.w;
        Bs[c4 + 0][row] = bv.x; Bs[c4 + 1][row] = bv.y;
        Bs[c4 + 2][row] = bv.z; Bs[c4 + 3][row] = bv.w;
      }
      __syncthreads();
#pragma unroll
      for (int k = 0; k < KB; ++k) {
        float4 a0 = *reinterpret_cast<const float4*>(&As[k][4 * ty]);
        float4 a1 = *reinterpret_cast<const float4*>(&As[k][64 + 4 * ty]);
        float4 b0 = *reinterpret_cast<const float4*>(&Bs[k][4 * tx]);
        float4 b1 = *reinterpret_cast<const float4*>(&Bs[k][64 + 4 * tx]);
        float a[8] = {a0.x, a0.y, a0.z, a0.w, a1.x, a1.y, a1.z, a1.w};
        float b[8] = {b0.x, b0.y, b0.z, b0.w, b1.x, b1.y, b1.z, b1.w};
#pragma unroll
        for (int r = 0; r < 8; ++r)
#pragma unroll
          for (int c = 0; c < 8; ++c)
            acc[r * 8 + c] = fmaf(a[r], b[c], acc[r * 8 + c]);
      }
      __syncthreads();
    }

    // selection update on v = sq_j - 2*dot (monotone in distance per anchor)
#pragma unroll
    for (int c = 0; c < 8; ++c) {
      int   j  = j0 + joff[c];
      int   jl = lab[j];
      float sj = sq[j];
#pragma unroll
      for (int r = 0; r < 8; ++r) {
        float v  = fmaf(-2.f, acc[r * 8 + c], sj);
        int   ig = i0 + ioff[r];
        if (jl == li[r]) {
          if (j != ig && v > bpv[r]) { bpv[r] = v; bpi[r] = j; }
        } else {
          if (v < bnv[r]) { bnv[r] = v; bni[r] = j; }
        }
      }
    }
  }

  // reduce across the 16 tx-lanes that share each anchor row
#pragma unroll
  for (int r = 0; r < 8; ++r) {
    float pvv = bpv[r]; int pii = bpi[r];
    float nvv = bnv[r]; int nii = bni[r];
#pragma unroll
    for (int m = 8; m > 0; m >>= 1) {
      float opv = __shfl_xor(pvv, m, 16); int opi = __shfl_xor(pii, m, 16);
      float onv = __shfl_xor(nvv, m, 16); int oni = __shfl_xor(nii, m, 16);
      if (opv > pvv) { pvv = opv; pii = opi; }
      if (onv < nvv) { nvv = onv; nii = oni; }
    }
    if (tx == 0) {
      int    i   = i0 + ioff[r];
      size_t idx = (size_t)blockIdx.y * B_N + i;
      pv[idx] = pvv; pi[idx] = pii;
      nv[idx] = nvv; ni[idx] = nii;
    }
  }
}

// ---------------- reduce partials + exact triplet distances + loss ----------------
__global__ void k_finish(const float* __restrict__ x,
                         const float* __restrict__ pv, const int* __restrict__ pi,
                         const float* __restrict__ nv, const int* __restrict__ ni,
                         float* __restrict__ sum, int* __restrict__ cnt) {
  int a    = blockIdx.x * 4 + (threadIdx.x >> 6);
  int lane = threadIdx.x & 63;

  float bpvv = -1e30f; int bpii = -1;
  float bnvv = 1e30f;  int bnii = -1;
#pragma unroll
  for (int p = 0; p < NJ; ++p) {
    size_t idx = (size_t)p * B_N + a;
    float v = pv[idx]; int ix = pi[idx];
    if (ix >= 0 && v > bpvv) { bpvv = v; bpii = ix; }
    float w = nv[idx]; int jx = ni[idx];
    if (jx >= 0 && w < bnvv) { bnvv = w; bnii = jx; }
  }
  bool valid = (bpii >= 0) && (bnii >= 0);
  int  pidx  = valid ? bpii : 0;
  int  nidx  = valid ? bnii : 0;

  float4 xa = *reinterpret_cast<const float4*>(x + (size_t)a * D_K + lane * 4);
  float4 xp = *reinterpret_cast<const float4*>(x + (size_t)pidx * D_K + lane * 4);
  float4 xn = *reinterpret_cast<const float4*>(x + (size_t)nidx * D_K + lane * 4);

  // F.pairwise_distance semantics: eps added to the per-component difference
  float dx, sp = 0.f, sn = 0.f;
  dx = xa.x - xp.x + 1e-6f; sp = fmaf(dx, dx, sp);
  dx = xa.y - xp.y + 1e-6f; sp = fmaf(dx, dx, sp);
  dx = xa.z - xp.z + 1e-6f; sp = fmaf(dx, dx, sp);
  dx = xa.w - xp.w + 1e-6f; sp = fmaf(dx, dx, sp);
  dx = xa.x - xn.x + 1e-6f; sn = fmaf(dx, dx, sn);
  dx = xa.y - xn.y + 1e-6f; sn = fmaf(dx, dx, sn);
  dx = xa.z - xn.z + 1e-6f; sn = fmaf(dx, dx, sn);
  dx = xa.w - xn.w + 1e-6f; sn = fmaf(dx, dx, sn);
#pragma unroll
  for (int off = 32; off > 0; off >>= 1) {
    sp += __shfl_down(sp, off, 64);
    sn += __shfl_down(sn, off, 64);
  }
  if (lane == 0 && valid) {
    float per = sqrtf(sp) - sqrtf(sn) + 0.3f;
    if (per > 0.f) {
      atomicAdd(sum, per);
    }
    atomicAdd(cnt, 1);
  }
}

__global__ void k_final(const float* __restrict__ sum, const int* __restrict__ cnt,
                        float* __restrict__ out) {
  if (threadIdx.x == 0) {
    int c = *cnt;
    if (c < 1) c = 1;
    out[0] = sum[0] / (float)c;
  }
}

extern "C" void kernel_launch(void* const* d_in, const int* in_sizes, int n_in,
                              void* d_out, int out_size, void* d_ws, size_t ws_size,
                              hipStream_t stream) {
  const float* x   = (const float*)d_in[0];
  const int*   lab = (const int*)d_in[1];  // labels converted to int32 by harness
  float*       out = (float*)d_out;

  char*  ws  = (char*)d_ws;
  float* sq  = (float*)ws;
  size_t off = (size_t)B_N * 4;
  size_t seg = (size_t)NJ * B_N * 4;
  float* pv  = (float*)(ws + off + 0 * seg);
  int*   pi  = (int*)(ws + off + 1 * seg);
  float* nv  = (float*)(ws + off + 2 * seg);
  int*   ni  = (int*)(ws + off + 3 * seg);
  float* sum = (float*)(ws + off + 4 * seg);
  int*   cnt = (int*)(sum + 1);

  hipMemsetAsync(sum, 0, 8, stream);
  k_rowsq<<<B_N / 4, 256, 0, stream>>>(x, sq);
  dim3 g(B_N / TI, NJ);
  k_mine<<<g, 256, 0, stream>>>(x, lab, sq, pv, pi, nv, ni);
  k_finish<<<B_N / 4, 256, 0, stream>>>(x, pv, pi, nv, ni, sum, cnt);
  k_final<<<1, 64, 0, stream>>>(sum, cnt, out);
}

// Round 2
// 240.074 us; speedup vs baseline: 2.8823x; 2.8823x over previous
//
#include <hip/hip_runtime.h>
#include <math.h>

// EnhancedTripletLoss, B=8192, D=256, 8 classes.
// R2: split-bf16 MFMA Gram mining (hi*hi + hi*lo + lo*hi), exact fp32 recompute
// of the mined triplet distances. Selection on v = sq_j - 2*dot (monotone).

typedef __attribute__((ext_vector_type(8))) short short8;
typedef __attribute__((ext_vector_type(4))) float floatx4;

#define B_N 8192
#define D_K 256
#define NJ  8          // j-chunks (grid.y); partials = NJ*2 (per wj half)
#define NP  16         // partial slots
#define TI  128
#define TJ  128
#define KC  32         // k-chunk per LDS stage (one MFMA k-step)
#define LDT 40         // LDS row stride in ushorts (32 + 8 pad = 80 B)

__device__ __forceinline__ unsigned short f2bf_rne(float f) {
  unsigned u = __float_as_uint(f);
  u += 0x7FFFu + ((u >> 16) & 1u);
  return (unsigned short)(u >> 16);
}

// ---------------- split fp32 -> bf16 hi/lo planes + row squared norms ----------------
__global__ void k_split(const float* __restrict__ x, unsigned short* __restrict__ xh,
                        unsigned short* __restrict__ xl, float* __restrict__ sq) {
  int row  = blockIdx.x * 4 + (threadIdx.x >> 6);
  int lane = threadIdx.x & 63;
  size_t off = (size_t)row * D_K + lane * 4;
  float4 v = *reinterpret_cast<const float4*>(x + off);
  float s = v.x * v.x + v.y * v.y + v.z * v.z + v.w * v.w;
  ushort4 h, l;
  float f, hf;
  f = v.x; h.x = f2bf_rne(f); hf = __uint_as_float((unsigned)h.x << 16); l.x = f2bf_rne(f - hf);
  f = v.y; h.y = f2bf_rne(f); hf = __uint_as_float((unsigned)h.y << 16); l.y = f2bf_rne(f - hf);
  f = v.z; h.z = f2bf_rne(f); hf = __uint_as_float((unsigned)h.z << 16); l.z = f2bf_rne(f - hf);
  f = v.w; h.w = f2bf_rne(f); hf = __uint_as_float((unsigned)h.w << 16); l.w = f2bf_rne(f - hf);
  *reinterpret_cast<ushort4*>(xh + off) = h;
  *reinterpret_cast<ushort4*>(xl + off) = l;
#pragma unroll
  for (int o = 32; o > 0; o >>= 1) s += __shfl_down(s, o, 64);
  if (lane == 0) sq[row] = s;
}

// ---------------- MFMA Gram + hard mining ----------------
// Block: 128 anchors x 1024 candidates (8 subtiles of 128). 4 waves in 2x2.
// Wave tile 64x64 = 4x4 MFMA 16x16 tiles; 3 MFMAs (hh, hl, lh) per tile per k-step.
__global__ __launch_bounds__(256, 2) void k_mine2(
    const unsigned short* __restrict__ xh, const unsigned short* __restrict__ xl,
    const int* __restrict__ lab, const float* __restrict__ sq,
    float* __restrict__ pv, int* __restrict__ pi,
    float* __restrict__ nv, int* __restrict__ ni) {
  __shared__ unsigned short Ah[TI * LDT], Al[TI * LDT];
  __shared__ unsigned short Bh[TJ * LDT], Bl[TJ * LDT];

  const int tid  = threadIdx.x;
  const int lane = tid & 63;
  const int w    = tid >> 6;
  const int wi   = w >> 1, wj = w & 1;
  const int quad = lane >> 4, l15 = lane & 15;
  const int i0   = blockIdx.x * TI;
  const int jblk = blockIdx.y * (B_N / NJ);

  // selection state: r = mt*4+reg -> i_r = i0 + wi*64 + mt*16 + quad*4 + reg
  float bpv[16], bnv[16];
  int   bpi[16], bni[16];
  unsigned lip0 = 0, lip1 = 0;  // 16 labels, 4 bits each
#pragma unroll
  for (int r = 0; r < 16; ++r) {
    bpv[r] = -1e30f; bnv[r] = 1e30f; bpi[r] = -1; bni[r] = -1;
    int ir = i0 + wi * 64 + (r >> 2) * 16 + quad * 4 + (r & 3);
    unsigned lv = (unsigned)lab[ir] & 0xFu;
    if (r < 8) lip0 |= lv << (r * 4); else lip1 |= lv << ((r - 8) * 4);
  }

  const int row0 = tid >> 2, c0 = tid & 3;
  const int ls0 = row0 * LDT + c0 * 8;
  const int ls1 = (row0 + 64) * LDT + c0 * 8;
  const int abase = (wi * 64 + l15) * LDT + quad * 8;
  const int bbase = (wj * 64 + l15) * LDT + quad * 8;

  short8 ga0, ga1, gal0, gal1, gb0, gb1, gbl0, gbl1;
  {
    size_t ao0 = (size_t)(i0 + row0) * D_K + c0 * 8;
    size_t ao1 = ao0 + (size_t)64 * D_K;
    size_t bo0 = (size_t)(jblk + row0) * D_K + c0 * 8;
    size_t bo1 = bo0 + (size_t)64 * D_K;
    ga0  = *(const short8*)(xh + ao0); ga1  = *(const short8*)(xh + ao1);
    gal0 = *(const short8*)(xl + ao0); gal1 = *(const short8*)(xl + ao1);
    gb0  = *(const short8*)(xh + bo0); gb1  = *(const short8*)(xh + bo1);
    gbl0 = *(const short8*)(xl + bo0); gbl1 = *(const short8*)(xl + bo1);
  }

  for (int sub = 0; sub < (B_N / NJ) / TJ; ++sub) {
    const int j0 = jblk + sub * TJ;
    floatx4 acc[16];
#pragma unroll
    for (int q = 0; q < 16; ++q) acc[q] = (floatx4)0.f;

    for (int ks = 0; ks < 8; ++ks) {
      __syncthreads();
      *(short8*)(Ah + ls0) = ga0;  *(short8*)(Ah + ls1) = ga1;
      *(short8*)(Al + ls0) = gal0; *(short8*)(Al + ls1) = gal1;
      *(short8*)(Bh + ls0) = gb0;  *(short8*)(Bh + ls1) = gb1;
      *(short8*)(Bl + ls0) = gbl0; *(short8*)(Bl + ls1) = gbl1;
      int nk = sub * 8 + ks + 1;
      if (nk < (B_N / NJ) / TJ * 8) {   // prefetch next k-chunk into regs
        int nsub = nk >> 3, nk0 = (nk & 7) * KC;
        size_t ao0 = (size_t)(i0 + row0) * D_K + nk0 + c0 * 8;
        size_t ao1 = ao0 + (size_t)64 * D_K;
        size_t bo0 = (size_t)(jblk + nsub * TJ + row0) * D_K + nk0 + c0 * 8;
        size_t bo1 = bo0 + (size_t)64 * D_K;
        ga0  = *(const short8*)(xh + ao0); ga1  = *(const short8*)(xh + ao1);
        gal0 = *(const short8*)(xl + ao0); gal1 = *(const short8*)(xl + ao1);
        gb0  = *(const short8*)(xh + bo0); gb1  = *(const short8*)(xh + bo1);
        gbl0 = *(const short8*)(xl + bo0); gbl1 = *(const short8*)(xl + bo1);
      }
      __syncthreads();

      short8 bhf[4], blf[4];
#pragma unroll
      for (int nt = 0; nt < 4; ++nt) {
        bhf[nt] = *(const short8*)(Bh + bbase + nt * 16 * LDT);
        blf[nt] = *(const short8*)(Bl + bbase + nt * 16 * LDT);
      }
#pragma unroll
      for (int mt = 0; mt < 4; ++mt) {
        short8 ahf = *(const short8*)(Ah + abase + mt * 16 * LDT);
        short8 alf = *(const short8*)(Al + abase + mt * 16 * LDT);
#pragma unroll
        for (int nt = 0; nt < 4; ++nt) {
          floatx4 c = acc[mt * 4 + nt];
          c = __builtin_amdgcn_mfma_f32_16x16x32_bf16(ahf, bhf[nt], c, 0, 0, 0);
          c = __builtin_amdgcn_mfma_f32_16x16x32_bf16(ahf, blf[nt], c, 0, 0, 0);
          c = __builtin_amdgcn_mfma_f32_16x16x32_bf16(alf, bhf[nt], c, 0, 0, 0);
          acc[mt * 4 + nt] = c;
        }
      }
    }

    // selection epilogue on v = sq_j - 2*dot
#pragma unroll
    for (int nt = 0; nt < 4; ++nt) {
      int   j  = j0 + wj * 64 + nt * 16 + l15;
      int   jl = lab[j];
      float sj = sq[j];
#pragma unroll
      for (int r = 0; r < 16; ++r) {
        int mt = r >> 2, reg = r & 3;
        float v  = fmaf(-2.f, acc[mt * 4 + nt][reg], sj);
        int   ir = i0 + wi * 64 + mt * 16 + quad * 4 + reg;
        unsigned lr = (r < 8 ? (lip0 >> (r * 4)) : (lip1 >> ((r - 8) * 4))) & 0xFu;
        if ((unsigned)jl == lr) {
          if (j != ir && v > bpv[r]) { bpv[r] = v; bpi[r] = j; }
        } else {
          if (v < bnv[r]) { bnv[r] = v; bni[r] = j; }
        }
      }
    }
  }

  // reduce across the 16 l15-lanes of each quad (xor<16 stays in-group)
#pragma unroll
  for (int r = 0; r < 16; ++r) {
    float pvv = bpv[r]; int pii = bpi[r];
    float nvv = bnv[r]; int nii = bni[r];
#pragma unroll
    for (int m = 1; m < 16; m <<= 1) {
      float o  = __shfl_xor(pvv, m); int oi  = __shfl_xor(pii, m);
      if (o > pvv) { pvv = o; pii = oi; }
      float o2 = __shfl_xor(nvv, m); int oi2 = __shfl_xor(nii, m);
      if (o2 < nvv) { nvv = o2; nii = oi2; }
    }
    if (l15 == 0) {
      int ir = i0 + wi * 64 + (r >> 2) * 16 + quad * 4 + (r & 3);
      size_t idx = (size_t)(blockIdx.y * 2 + wj) * B_N + ir;
      pv[idx] = pvv; pi[idx] = pii;
      nv[idx] = nvv; ni[idx] = nii;
    }
  }
}

// ---------------- reduce partials + exact fp32 triplet distances + loss ----------------
__global__ void k_finish(const float* __restrict__ x,
                         const float* __restrict__ pv, const int* __restrict__ pi,
                         const float* __restrict__ nv, const int* __restrict__ ni,
                         float* __restrict__ sum, int* __restrict__ cnt) {
  __shared__ float ssum[4];
  __shared__ int   scnt[4];
  int w = threadIdx.x >> 6, lane = threadIdx.x & 63;
  float lsum = 0.f; int lcnt = 0;
  for (int it = 0; it < 32; ++it) {
    int a = (blockIdx.x * 4 + w) * 32 + it;
    float bpvv = -1e30f; int bpii = -1;
    float bnvv = 1e30f;  int bnii = -1;
    if (lane < NP) {
      size_t idx = (size_t)lane * B_N + a;
      float v = pv[idx]; int ix = pi[idx];
      if (ix >= 0) { bpvv = v; bpii = ix; }
      float u = nv[idx]; int jx = ni[idx];
      if (jx >= 0) { bnvv = u; bnii = jx; }
    }
#pragma unroll
    for (int m = 1; m < 16; m <<= 1) {
      float o  = __shfl_xor(bpvv, m); int oi  = __shfl_xor(bpii, m);
      if (o > bpvv) { bpvv = o; bpii = oi; }
      float o2 = __shfl_xor(bnvv, m); int oi2 = __shfl_xor(bnii, m);
      if (o2 < bnvv) { bnvv = o2; bnii = oi2; }
    }
    bpii = __shfl(bpii, 0); bnii = __shfl(bnii, 0);
    bool valid = (bpii >= 0) && (bnii >= 0);
    int  pidx = valid ? bpii : 0;
    int  nidx = valid ? bnii : 0;

    float4 xa = *reinterpret_cast<const float4*>(x + (size_t)a * D_K + lane * 4);
    float4 xp = *reinterpret_cast<const float4*>(x + (size_t)pidx * D_K + lane * 4);
    float4 xn = *reinterpret_cast<const float4*>(x + (size_t)nidx * D_K + lane * 4);
    float dx, sp = 0.f, sn = 0.f;
    dx = xa.x - xp.x + 1e-6f; sp = fmaf(dx, dx, sp);
    dx = xa.y - xp.y + 1e-6f; sp = fmaf(dx, dx, sp);
    dx = xa.z - xp.z + 1e-6f; sp = fmaf(dx, dx, sp);
    dx = xa.w - xp.w + 1e-6f; sp = fmaf(dx, dx, sp);
    dx = xa.x - xn.x + 1e-6f; sn = fmaf(dx, dx, sn);
    dx = xa.y - xn.y + 1e-6f; sn = fmaf(dx, dx, sn);
    dx = xa.z - xn.z + 1e-6f; sn = fmaf(dx, dx, sn);
    dx = xa.w - xn.w + 1e-6f; sn = fmaf(dx, dx, sn);
#pragma unroll
    for (int o = 32; o > 0; o >>= 1) {
      sp += __shfl_down(sp, o, 64);
      sn += __shfl_down(sn, o, 64);
    }
    if (lane == 0 && valid) {
      float per = sqrtf(sp) - sqrtf(sn) + 0.3f;
      if (per > 0.f) lsum += per;
      lcnt += 1;
    }
  }
  if (lane == 0) { ssum[w] = lsum; scnt[w] = lcnt; }
  __syncthreads();
  if (threadIdx.x == 0) {
    atomicAdd(sum, ssum[0] + ssum[1] + ssum[2] + ssum[3]);
    atomicAdd(cnt, scnt[0] + scnt[1] + scnt[2] + scnt[3]);
  }
}

__global__ void k_final(const float* __restrict__ sum, const int* __restrict__ cnt,
                        float* __restrict__ out) {
  if (threadIdx.x == 0) {
    int c = *cnt;
    if (c < 1) c = 1;
    out[0] = sum[0] / (float)c;
  }
}

extern "C" void kernel_launch(void* const* d_in, const int* in_sizes, int n_in,
                              void* d_out, int out_size, void* d_ws, size_t ws_size,
                              hipStream_t stream) {
  const float* x   = (const float*)d_in[0];
  const int*   lab = (const int*)d_in[1];
  float*       out = (float*)d_out;

  char* ws = (char*)d_ws;
  unsigned short* xh = (unsigned short*)ws;                       // 4 MB
  unsigned short* xl = (unsigned short*)(ws + (size_t)4 * 1024 * 1024);
  float* sq = (float*)(ws + (size_t)8 * 1024 * 1024);             // 32 KB
  char*  pb = ws + (size_t)8 * 1024 * 1024 + 65536;
  size_t seg = (size_t)NP * B_N * 4;                              // 512 KB each
  float* pv = (float*)(pb + 0 * seg);
  int*   pi = (int*)(pb + 1 * seg);
  float* nv = (float*)(pb + 2 * seg);
  int*   ni = (int*)(pb + 3 * seg);
  float* sum = (float*)(pb + 4 * seg);
  int*   cnt = (int*)(sum + 1);

  hipMemsetAsync(sum, 0, 8, stream);
  k_split<<<B_N / 4, 256, 0, stream>>>(x, xh, xl, sq);
  dim3 g(B_N / TI, NJ);
  k_mine2<<<g, 256, 0, stream>>>(xh, xl, lab, sq, pv, pi, nv, ni);
  k_finish<<<64, 256, 0, stream>>>(x, pv, pi, nv, ni, sum, cnt);
  k_final<<<1, 64, 0, stream>>>(sum, cnt, out);
}